// Round 4
// baseline (196.404 us; speedup 1.0000x reference)
//
#include <hip/hip_runtime.h>

constexpr int kB    = 16;
constexpr int kM    = 512;
constexpr int kS    = 32;
constexpr int kE    = 128;
constexpr int kV    = 32000;
constexpr int kVN   = kV - 1;   // nil (zero) row index

// -------------------------------------------------------------------------
// Kernel 1: story embeddings (R6-proven, untouched; bar machinery removed).
// 2 rows per 256-thread block, grid = 4096. Streams 268 MB of 512B
// random-gather traffic at the memory-system rate (~6.6 TB/s) -> ~40.5 µs
// structural floor. enc[s][e] = 1 + (e-63)(s-15)/1024 (exact f32 match).
// -------------------------------------------------------------------------
__global__ __launch_bounds__(256) void embed_stories_kernel(
    const int*   __restrict__ stories,   // [B,M,S]
    const float* __restrict__ st_bias,   // [VN,E]
    const float* __restrict__ out_bias,  // [VN,E]
    const float* __restrict__ mem_bias,  // [M,E]
    float*       __restrict__ memory,    // [B,M,E]
    float*       __restrict__ output)    // [B,M,E]
{
    __shared__ int sidx[2][kS];
    __shared__ __align__(16) float pm[8][kE];
    __shared__ __align__(16) float po[8][kE];

    const int t    = threadIdx.x;
    const int row0 = blockIdx.x * 2;
    if (t < 64) sidx[t >> 5][t & 31] = stories[row0 * kS + t];
    __syncthreads();

    const int g    = t >> 5;
    const int lane = t & 31;
    const int p    = g >> 2;       // row of pair
    const int ph   = g & 3;        // s-phase
    const int e0   = lane * 4;
    const float ef0 = (float)(e0 - 63), ef1 = (float)(e0 - 62);
    const float ef2 = (float)(e0 - 61), ef3 = (float)(e0 - 60);

    float4 am = {0.f, 0.f, 0.f, 0.f};
    float4 ao = {0.f, 0.f, 0.f, 0.f};
    #pragma unroll
    for (int j = 0; j < 8; ++j) {
        const int s   = ph * 8 + j;
        const int idx = sidx[p][s];
        const int ci  = idx < kVN ? idx : (kVN - 1);       // clamped row
        const float live = (idx < kVN) ? 1.0f : 0.0f;      // nil -> weight 0
        const float sf = (float)(s - 15) * (1.0f / 1024.0f);
        const float4 vm = *(const float4*)(st_bias  + (size_t)ci * kE + e0);
        const float4 vo = *(const float4*)(out_bias + (size_t)ci * kE + e0);
        const float c0 = fmaf(ef0, sf, 1.0f) * live;
        const float c1 = fmaf(ef1, sf, 1.0f) * live;
        const float c2 = fmaf(ef2, sf, 1.0f) * live;
        const float c3 = fmaf(ef3, sf, 1.0f) * live;
        am.x = fmaf(vm.x, c0, am.x); am.y = fmaf(vm.y, c1, am.y);
        am.z = fmaf(vm.z, c2, am.z); am.w = fmaf(vm.w, c3, am.w);
        ao.x = fmaf(vo.x, c0, ao.x); ao.y = fmaf(vo.y, c1, ao.y);
        ao.z = fmaf(vo.z, c2, ao.z); ao.w = fmaf(vo.w, c3, ao.w);
    }
    *(float4*)&pm[g][e0] = am;
    *(float4*)&po[g][e0] = ao;
    __syncthreads();

    const int pr = t >> 7;
    const int e  = t & 127;
    const int row = row0 + pr;
    const int m   = row & (kM - 1);
    const float sm = pm[pr * 4 + 0][e] + pm[pr * 4 + 1][e] +
                     pm[pr * 4 + 2][e] + pm[pr * 4 + 3][e];
    const float so = po[pr * 4 + 0][e] + po[pr * 4 + 1][e] +
                     po[pr * 4 + 2][e] + po[pr * 4 + 3][e];
    memory[(size_t)row * kE + e] = sm + mem_bias[m * kE + e];
    output[(size_t)row * kE + e] = so;
}

// -------------------------------------------------------------------------
// Kernel 2 (R14): q-embed + 3 hops, ONE BLOCK PER BATCH ELEMENT (16 blocks
// x 1024 threads). Zero cross-block synchronization — R12/R13 showed each
// barrier/exchange round costs ~2-6 µs (LLC RMW serialization + skew +
// spin-poll granularity), dominating the microscopic per-hop FLOPs.
// mem/out are NOT staged: scores and numer stream them from cache
// (hop 0: LLC, written by embed; hops 1-2: own XCD L2 — 2 blocks/XCD
// x 512 KB = 1 MB << 4 MB). All reductions are intra-block LDS/shfl.
// -------------------------------------------------------------------------
__global__ __launch_bounds__(1024) void hops16_kernel(
    const int*   __restrict__ queries,   // [B,S]
    const float* __restrict__ q_bias,    // [VN,E]
    const float* __restrict__ memory,    // [B,M,E]
    const float* __restrict__ output,    // [B,M,E]
    const float* __restrict__ w_int,     // [E,E]
    const float* __restrict__ w_out,     // [E,E]
    float*       __restrict__ xg)        // [E,B] transposed relu_x
{
    __shared__ __align__(16) float part8[8][kE];
    __shared__ float sc[kM];
    __shared__ __align__(16) float q_s[kE];
    __shared__ float xb[kE];
    __shared__ float ds_s;

    const int b = blockIdx.x;
    const int t = threadIdx.x;
    const float* memb = memory + (size_t)b * kM * kE;
    const float* outb = output + (size_t)b * kM * kE;

    // ---- q-embed (proven path: 8 groups x 32 lanes, 4 gathers/thread) ----
    if (t < 256) {
        const int g = t >> 5, lane = t & 31, e0 = lane * 4;
        const float f0 = (float)(e0 - 63) * (1.0f / 1024.0f);
        const float f1 = (float)(e0 - 62) * (1.0f / 1024.0f);
        const float f2 = (float)(e0 - 61) * (1.0f / 1024.0f);
        const float f3 = (float)(e0 - 60) * (1.0f / 1024.0f);
        float4 a = {0.f, 0.f, 0.f, 0.f};
        #pragma unroll
        for (int j = 0; j < 4; ++j) {
            const int s   = g * 4 + j;
            const int idx = queries[b * kS + s];
            const int ci  = idx < kVN ? idx : (kVN - 1);
            const float live = (idx < kVN) ? 1.0f : 0.0f;
            const float sf = (float)(s - 15);
            const float4 v = *(const float4*)&q_bias[(size_t)ci * kE + e0];
            a.x = fmaf(v.x, fmaf(f0, sf, 1.f) * live, a.x);
            a.y = fmaf(v.y, fmaf(f1, sf, 1.f) * live, a.y);
            a.z = fmaf(v.z, fmaf(f2, sf, 1.f) * live, a.z);
            a.w = fmaf(v.w, fmaf(f3, sf, 1.f) * live, a.w);
        }
        *(float4*)&part8[g][e0] = a;
    }
    __syncthreads();
    if (t < kE) {
        float s = 0.f;
        #pragma unroll
        for (int g = 0; g < 8; ++g) s += part8[g][t];
        q_s[t] = s;
    }
    __syncthreads();

    for (int hop = 0; hop < 3; ++hop) {
        // ---- scores: 2 threads per row (512 rows), 64 e each ----
        {
            const int rw = t >> 1, h = t & 1;
            const float4* mv = (const float4*)(memb + (size_t)rw * kE + h * 64);
            const float4* qv = (const float4*)(q_s + h * 64);
            float d = 0.f;
            #pragma unroll
            for (int i = 0; i < 16; ++i) {
                const float4 m4 = mv[i], q4 = qv[i];
                d = fmaf(m4.x, q4.x, d); d = fmaf(m4.y, q4.y, d);
                d = fmaf(m4.z, q4.z, d); d = fmaf(m4.w, q4.w, d);
            }
            d += __shfl_xor(d, 1);
            if (h == 0) sc[rw] = __expf(d);   // no max-sub: |s| = O(1)
        }
        __syncthreads();

        // ---- denom: wave 0 reduces sc[512] ----
        if (t < 64) {
            float s = 0.f;
            #pragma unroll
            for (int j = 0; j < 8; ++j) s += sc[t + 64 * j];
            #pragma unroll
            for (int off = 32; off; off >>= 1) s += __shfl_down(s, off);
            if (t == 0) ds_s = s;
        }

        // ---- numer: 8 groups of 128 threads, 64 rows each, stream outb ----
        {
            const int grp = t >> 7, e = t & 127;
            const float* og = outb + (size_t)grp * 64 * kE + e;
            float acc = 0.f;
            #pragma unroll 16
            for (int j = 0; j < 64; ++j)
                acc = fmaf(sc[grp * 64 + j], og[j * kE], acc);
            part8[grp][e] = acc;
        }
        __syncthreads();

        // ---- combine: xb = q + numer/denom (all-local) ----
        if (t < kE) {
            float ns = 0.f;
            #pragma unroll
            for (int g = 0; g < 8; ++g) ns += part8[g][t];
            xb[t] = q_s[t] + ns / ds_s;
        }
        __syncthreads();

        // ---- q' = xb @ W (8 k-groups of 16) ----
        {
            const int grp = t >> 7, e = t & 127;
            const float* w = (hop == 2) ? w_out : w_int;
            float acc = 0.f;
            #pragma unroll
            for (int j = 0; j < 16; ++j) {
                const int k = grp * 16 + j;
                acc = fmaf(xb[k], w[k * kE + e], acc);
            }
            part8[grp][e] = acc;
        }
        __syncthreads();
        if (t < kE) {
            float s = 0.f;
            #pragma unroll
            for (int g = 0; g < 8; ++g) s += part8[g][t];
            q_s[t] = s;
        }
        __syncthreads();
    }

    // relu + transposed store; visibility to final_kernel via the kernel
    // boundary (stream-ordered dispatch performs the release/acquire).
    if (t < kE) xg[t * kB + b] = fmaxf(q_s[t], 0.f);
}

// -------------------------------------------------------------------------
// Kernel 3: out[b,v] = sum_e relu_x[b,e] * w_final[e,v]. (R6-proven,
// round-0 version verbatim.) 250 blocks x 256 threads: v = bid*128 +
// (t&127), e-half = t>>7. xg read transposed -> uniform scalar loads;
// halves combined via LDS.
// -------------------------------------------------------------------------
__global__ __launch_bounds__(256) void final_kernel(
    const float* __restrict__ xg,   // [E,B]
    const float* __restrict__ wf,   // [E,V]
    float*       __restrict__ out)  // [B,V]
{
    __shared__ float ps[128 * kB];
    const int t = threadIdx.x;
    const int v = blockIdx.x * 128 + (t & 127);
    const int h = t >> 7;

    float acc[kB];
    #pragma unroll
    for (int b = 0; b < kB; ++b) acc[b] = 0.f;

    const int e0 = h * 64;
    #pragma unroll 4
    for (int ei = 0; ei < 64; ++ei) {
        const int e = e0 + ei;
        const float wv = wf[(size_t)e * kV + v];
        const float* xr = xg + e * kB;
        #pragma unroll
        for (int b = 0; b < kB; ++b) acc[b] = fmaf(xr[b], wv, acc[b]);
    }
    if (h == 1) {
        #pragma unroll
        for (int b = 0; b < kB; ++b) ps[(t & 127) * kB + b] = acc[b];
    }
    __syncthreads();
    if (h == 0) {
        #pragma unroll
        for (int b = 0; b < kB; ++b)
            out[(size_t)b * kV + v] = acc[b] + ps[(t & 127) * kB + b];
    }
}

// -------------------------------------------------------------------------
extern "C" void kernel_launch(void* const* d_in, const int* in_sizes, int n_in,
                              void* d_out, int out_size, void* d_ws, size_t ws_size,
                              hipStream_t stream)
{
    const int*   queries  = (const int*)  d_in[0];
    const int*   stories  = (const int*)  d_in[1];
    const float* q_bias   = (const float*)d_in[2];
    const float* st_bias  = (const float*)d_in[3];
    const float* mem_bias = (const float*)d_in[4];
    const float* out_bias = (const float*)d_in[5];
    const float* w_int    = (const float*)d_in[6];
    const float* w_out    = (const float*)d_in[7];
    const float* w_final  = (const float*)d_in[8];
    float* out = (float*)d_out;

    // ws layout (floats): memory | output | xg
    float* memory = (float*)d_ws;
    float* output = memory + (size_t)kB * kM * kE;        // 1,048,576
    float* xg     = output + (size_t)kB * kM * kE;        // 1,048,576

    embed_stories_kernel<<<dim3((kB * kM) / 2), dim3(256), 0, stream>>>(
        stories, st_bias, out_bias, mem_bias, memory, output);

    hops16_kernel<<<dim3(kB), dim3(1024), 0, stream>>>(
        queries, q_bias, memory, output, w_int, w_out, xg);

    final_kernel<<<dim3(kV / 128), dim3(256), 0, stream>>>(xg, w_final, out);
}

// Round 5
// 178.141 us; speedup vs baseline: 1.1025x; 1.1025x over previous
//
#include <hip/hip_runtime.h>

constexpr int kB    = 16;
constexpr int kM    = 512;
constexpr int kS    = 32;
constexpr int kE    = 128;
constexpr int kV    = 32000;
constexpr int kVN   = kV - 1;   // nil (zero) row index
constexpr int kMS   = 132;      // padded LDS stride for hops mem tile

// -------------------------------------------------------------------------
// Kernel 1: story embeddings (R6-proven, untouched). 2 rows per 256-thread
// block, grid = 4096. Streams 268 MB of 512B gather traffic at the
// memory-system rate (~6.6 TB/s) -> ~40.5 µs structural floor.
// enc[s][e] = 1 + (e-63)(s-15)/1024 (exact f32 match of numpy formula).
// Block 0 zeroes the 192 denom flags (3 hops x 16 b x 4 qtr) — these are
// the data-as-flag sync words for the hops kernel (R15), and the workspace
// poison must never be able to pre-set them.
// -------------------------------------------------------------------------
__global__ __launch_bounds__(256) void embed_stories_kernel(
    const int*   __restrict__ stories,   // [B,M,S]
    const float* __restrict__ st_bias,   // [VN,E]
    const float* __restrict__ out_bias,  // [VN,E]
    const float* __restrict__ mem_bias,  // [M,E]
    float*       __restrict__ memory,    // [B,M,E]
    float*       __restrict__ output,    // [B,M,E]
    float*       __restrict__ denom)     // [3,B,4] flags -> zeroed by block 0
{
    __shared__ int sidx[2][kS];
    __shared__ __align__(16) float pm[8][kE];
    __shared__ __align__(16) float po[8][kE];

    const int t    = threadIdx.x;
    const int row0 = blockIdx.x * 2;
    if (t < 64) sidx[t >> 5][t & 31] = stories[row0 * kS + t];
    if (blockIdx.x == 0 && t < 3 * kB * 4) denom[t] = 0.f;
    __syncthreads();

    const int g    = t >> 5;
    const int lane = t & 31;
    const int p    = g >> 2;       // row of pair
    const int ph   = g & 3;        // s-phase
    const int e0   = lane * 4;
    const float ef0 = (float)(e0 - 63), ef1 = (float)(e0 - 62);
    const float ef2 = (float)(e0 - 61), ef3 = (float)(e0 - 60);

    float4 am = {0.f, 0.f, 0.f, 0.f};
    float4 ao = {0.f, 0.f, 0.f, 0.f};
    #pragma unroll
    for (int j = 0; j < 8; ++j) {
        const int s   = ph * 8 + j;
        const int idx = sidx[p][s];
        const int ci  = idx < kVN ? idx : (kVN - 1);       // clamped row
        const float live = (idx < kVN) ? 1.0f : 0.0f;      // nil -> weight 0
        const float sf = (float)(s - 15) * (1.0f / 1024.0f);
        const float4 vm = *(const float4*)(st_bias  + (size_t)ci * kE + e0);
        const float4 vo = *(const float4*)(out_bias + (size_t)ci * kE + e0);
        const float c0 = fmaf(ef0, sf, 1.0f) * live;
        const float c1 = fmaf(ef1, sf, 1.0f) * live;
        const float c2 = fmaf(ef2, sf, 1.0f) * live;
        const float c3 = fmaf(ef3, sf, 1.0f) * live;
        am.x = fmaf(vm.x, c0, am.x); am.y = fmaf(vm.y, c1, am.y);
        am.z = fmaf(vm.z, c2, am.z); am.w = fmaf(vm.w, c3, am.w);
        ao.x = fmaf(vo.x, c0, ao.x); ao.y = fmaf(vo.y, c1, ao.y);
        ao.z = fmaf(vo.z, c2, ao.z); ao.w = fmaf(vo.w, c3, ao.w);
    }
    *(float4*)&pm[g][e0] = am;
    *(float4*)&po[g][e0] = ao;
    __syncthreads();

    const int pr = t >> 7;
    const int e  = t & 127;
    const int row = row0 + pr;
    const int m   = row & (kM - 1);
    const float sm = pm[pr * 4 + 0][e] + pm[pr * 4 + 1][e] +
                     pm[pr * 4 + 2][e] + pm[pr * 4 + 3][e];
    const float so = po[pr * 4 + 0][e] + po[pr * 4 + 1][e] +
                     po[pr * 4 + 2][e] + po[pr * 4 + 3][e];
    memory[(size_t)row * kE + e] = sm + mem_bias[m * kE + e];
    output[(size_t)row * kE + e] = so;
}

// Agent-scope relaxed load/store (device coherence point; R3-proven).
__device__ __forceinline__ void cstore(float* p, float v) {
    __hip_atomic_store(p, v, __ATOMIC_RELAXED, __HIP_MEMORY_SCOPE_AGENT);
}
__device__ __forceinline__ float cload(const float* p) {
    return __hip_atomic_load(p, __ATOMIC_RELAXED, __HIP_MEMORY_SCOPE_AGENT);
}

// -------------------------------------------------------------------------
// Kernel 2 (R15): q-embed + 3 hops + fused final. 64 blocks x 1024 threads,
// b = bid&15 (4 blocks/group, XCD-colocated), qtr = bid>>4, 128 rows/block
// — the R2-proven structure. Sync rework:
//  * counter barriers -> data-as-flag: producer release-stores its denom
//    partial (sum of exps, provably > 0) after __syncthreads drains the
//    numer cstores; consumers poll the flags != 0 (relaxed, as the proven
//    counter spin did) then read numer.
//  * hop-2 wait is GLOBAL (all 64 flags): qtr==0 blocks published q2 after
//    hop 1, so every block then computes xb/relu for ALL 16 b locally into
//    LDS and runs the wf tail with zero further sync. This deletes the
//    old round-4 all-barrier, the xg global round-trip, and the separate
//    final kernel launch.
// -------------------------------------------------------------------------
__global__ __launch_bounds__(1024) void hops_final_kernel(
    const int*   __restrict__ queries,   // [B,S]
    const float* __restrict__ q_bias,    // [VN,E]
    const float* __restrict__ memory,    // [B,M,E]
    const float* __restrict__ output,    // [B,M,E]
    const float* __restrict__ w_int,     // [E,E]
    const float* __restrict__ w_out,     // [E,E]
    const float* __restrict__ wf,        // [E,V]
    float*       __restrict__ numer,     // [3,B,4,E]
    float*                    denom,     // [3,B,4]  (flags; pre-zeroed)
    float*                    q2,        // [B,E]    hop-1 state publish
    float*       __restrict__ out)       // [B,V]
{
    __shared__ __align__(16) float pool[128 * kMS + 128 * kE];
    __shared__ __align__(16) float part8[8][kE];
    __shared__ float sc_q[128];
    __shared__ __align__(16) float q_s[kE];
    __shared__ float xb[kE];
    __shared__ float dtmp;

    float* mem_lds = pool;                      // [128][kMS] (hops)
    float* out_lds = pool + 128 * kMS;          // [128][kE]  (hops)

    const int bid = blockIdx.x;
    const int b   = bid & 15;      // XCD-colocated groups (bids ≡ b mod 16)
    const int qtr = bid >> 4;
    const int t   = threadIdx.x;

    // ---- stage this quarter's 128 mem/out rows into LDS ----
    const float* memb = memory + ((size_t)b * kM + qtr * 128) * kE;
    const float* outb = output + ((size_t)b * kM + qtr * 128) * kE;
    #pragma unroll
    for (int i = 0; i < 4; ++i) {
        const int flat = t + i * 1024;
        const int rr = flat >> 5, ff = (flat & 31) * 4;
        *(float4*)&mem_lds[rr * kMS + ff] = *(const float4*)&memb[(size_t)rr * kE + ff];
        *(float4*)&out_lds[rr * kE  + ff] = *(const float4*)&outb[(size_t)rr * kE + ff];
    }

    // ---- q-embed: gathers issue concurrently with the staging above ----
    if (t < 256) {
        const int g = t >> 5, lane = t & 31, e0 = lane * 4;
        const float f0 = (float)(e0 - 63) * (1.0f / 1024.0f);
        const float f1 = (float)(e0 - 62) * (1.0f / 1024.0f);
        const float f2 = (float)(e0 - 61) * (1.0f / 1024.0f);
        const float f3 = (float)(e0 - 60) * (1.0f / 1024.0f);
        float4 a = {0.f, 0.f, 0.f, 0.f};
        #pragma unroll
        for (int j = 0; j < 4; ++j) {
            const int s   = g * 4 + j;
            const int idx = queries[b * kS + s];          // L1-hot, 2 KB table
            const int ci  = idx < kVN ? idx : (kVN - 1);
            const float live = (idx < kVN) ? 1.0f : 0.0f;
            const float sf = (float)(s - 15);
            const float4 v = *(const float4*)&q_bias[(size_t)ci * kE + e0];
            a.x = fmaf(v.x, fmaf(f0, sf, 1.f) * live, a.x);
            a.y = fmaf(v.y, fmaf(f1, sf, 1.f) * live, a.y);
            a.z = fmaf(v.z, fmaf(f2, sf, 1.f) * live, a.z);
            a.w = fmaf(v.w, fmaf(f3, sf, 1.f) * live, a.w);
        }
        *(float4*)&part8[g][e0] = a;
    }
    __syncthreads();
    if (t < kE) {
        float s = 0.f;
        #pragma unroll
        for (int g = 0; g < 8; ++g) s += part8[g][t];
        q_s[t] = s;
    }
    __syncthreads();

    for (int hop = 0; hop < 3; ++hop) {
        // ---- scores for own 128 rows: 8 lanes x 16 e per row ----
        {
            const int rw = t >> 3, sub = t & 7;
            const float4* qv = (const float4*)&q_s[sub * 16];
            const float4* mv = (const float4*)&mem_lds[rw * kMS + sub * 16];
            float d = 0.f;
            #pragma unroll
            for (int i = 0; i < 4; ++i) {
                const float4 m4 = mv[i], q4 = qv[i];
                d = fmaf(m4.x, q4.x, d); d = fmaf(m4.y, q4.y, d);
                d = fmaf(m4.z, q4.z, d); d = fmaf(m4.w, q4.w, d);
            }
            d += __shfl_down(d, 4);
            d += __shfl_down(d, 2);
            d += __shfl_down(d, 1);
            if (sub == 0) sc_q[rw] = __expf(d);   // no max-sub: |s| = O(1)
        }
        __syncthreads();

        // ---- numer partial ----
        {
            const int grp = t >> 7, e = t & 127;
            float acc = 0.f;
            const float* pp = &sc_q[grp * 16];
            const float* ob = &out_lds[grp * 16 * kE + e];
            #pragma unroll
            for (int j = 0; j < 16; ++j)
                acc = fmaf(pp[j], ob[j * kE], acc);
            part8[grp][e] = acc;
        }
        __syncthreads();

        // ---- publish partials; denom doubles as the readiness flag ----
        float* nq = numer + (((size_t)hop * kB + b) * 4 + qtr) * kE;
        if (t < kE) {
            float s = 0.f;
            #pragma unroll
            for (int g = 0; g < 8; ++g) s += part8[g][t];
            cstore(&nq[t], s);
        } else if (t < 192) {
            const int l = t - 128;
            float s2 = sc_q[l] + sc_q[l + 64];
            #pragma unroll
            for (int off = 32; off; off >>= 1) s2 += __shfl_down(s2, off);
            if (l == 0) dtmp = s2;
        }
        __syncthreads();   // drains all numer cstores (vmcnt 0 before barrier)
        if (t == 0)
            __hip_atomic_store(&denom[hop * kB * 4 + b * 4 + qtr], dtmp,
                               __ATOMIC_RELEASE, __HIP_MEMORY_SCOPE_AGENT);

        // ---- flag wait: hops 0/1 own 4 flags; hop 2 all 64 ----
        {
            const float* df = denom + hop * kB * 4;
            if (hop < 2) {
                if (t < 4) {
                    while (cload(&df[b * 4 + t]) == 0.f)
                        __builtin_amdgcn_s_sleep(1);
                }
            } else {
                if (t < 64) {
                    while (cload(&df[t]) == 0.f)
                        __builtin_amdgcn_s_sleep(1);
                }
            }
        }
        __syncthreads();

        if (hop < 2) {
            // ---- combine own b: xb = q + sum(numer)/sum(denom) ----
            if (t < kE) {
                const float* nn = numer + ((size_t)hop * kB + b) * 4 * kE;
                const float* dd = denom + hop * kB * 4 + b * 4;
                const float ns = cload(&nn[t]) + cload(&nn[kE + t]) +
                                 cload(&nn[2 * kE + t]) + cload(&nn[3 * kE + t]);
                const float ds = cload(&dd[0]) + cload(&dd[1]) +
                                 cload(&dd[2]) + cload(&dd[3]);
                xb[t] = q_s[t] + ns / ds;
            }
            __syncthreads();

            // ---- q' = xb @ w_int (8 k-groups of 16) ----
            {
                const int grp = t >> 7, e = t & 127;
                float acc = 0.f;
                #pragma unroll
                for (int j = 0; j < 16; ++j) {
                    const int k = grp * 16 + j;
                    acc = fmaf(xb[k], w_int[k * kE + e], acc);
                }
                part8[grp][e] = acc;
            }
            __syncthreads();
            if (t < kE) {
                float s = 0.f;
                #pragma unroll
                for (int g = 0; g < 8; ++g) s += part8[g][t];
                q_s[t] = s;
                // publish hop-1 state for the hop-2 global combine; drained
                // (and thus release-ordered) by hop-2's denom publish.
                if (hop == 1 && qtr == 0) cstore(&q2[b * kE + t], s);
            }
            __syncthreads();
        }
    }

    // ---- hop-2 global combine: xb/relu for ALL 16 b, locally ----
    // pool is dead (scores/numer done); reuse as xall[16][kE] + sx[16][kE].
    float* xall = pool;
    float* sx   = pool + kB * kE;
    {
        const int g8 = t >> 7, e = t & 127;
        const float* nn2 = numer + (size_t)2 * kB * 4 * kE;
        const float* dd2 = denom + 2 * kB * 4;
        #pragma unroll
        for (int half = 0; half < 2; ++half) {
            const int bb = g8 + half * 8;
            float ns = 0.f, ds = 0.f;
            #pragma unroll
            for (int j = 0; j < 4; ++j) ns += cload(&nn2[(bb * 4 + j) * kE + e]);
            #pragma unroll
            for (int j = 0; j < 4; ++j) ds += cload(&dd2[bb * 4 + j]);
            xall[bb * kE + e] = cload(&q2[bb * kE + e]) + ns / ds;
        }
    }
    __syncthreads();
    {
        const int g8 = t >> 7, e = t & 127;
        #pragma unroll
        for (int half = 0; half < 2; ++half) {
            const int bb = g8 + half * 8;
            float acc = 0.f;
            #pragma unroll 8
            for (int k = 0; k < kE; ++k)
                acc = fmaf(xall[bb * kE + k], w_out[k * kE + e], acc);
            sx[bb * kE + e] = fmaxf(acc, 0.f);
        }
    }
    __syncthreads();

    // ---- fused final: out[b, v] = relu_x[b,:] . wf[:, v] ----
    // 500 v-columns per block (64 x 500 = 32000); 512 v-lanes x 2 e-halves;
    // halves combined via LDS ps[b][vt] (stride-1). Only global loads in
    // the loop are the coalesced wf stream; sx reads are LDS broadcasts.
    {
        const int vt = t & 511;
        const int h  = t >> 9;
        const int v  = bid * 500 + vt;
        float* ps = out_lds;                    // reuse: 16*512*4 = 32 KB
        float acc[kB];
        #pragma unroll
        for (int b2 = 0; b2 < kB; ++b2) acc[b2] = 0.f;

        if (vt < 500) {
            const int e0 = h * 64;
            #pragma unroll 8
            for (int ei = 0; ei < 64; ++ei) {
                const int e = e0 + ei;
                const float wv = wf[(size_t)e * kV + v];
                #pragma unroll
                for (int b2 = 0; b2 < kB; ++b2)
                    acc[b2] = fmaf(sx[b2 * kE + e], wv, acc[b2]);
            }
            if (h == 1) {
                #pragma unroll
                for (int b2 = 0; b2 < kB; ++b2) ps[b2 * 512 + vt] = acc[b2];
            }
        }
        __syncthreads();
        if (h == 0 && vt < 500) {
            #pragma unroll
            for (int b2 = 0; b2 < kB; ++b2)
                out[(size_t)b2 * kV + v] = acc[b2] + ps[b2 * 512 + vt];
        }
    }
}

// -------------------------------------------------------------------------
extern "C" void kernel_launch(void* const* d_in, const int* in_sizes, int n_in,
                              void* d_out, int out_size, void* d_ws, size_t ws_size,
                              hipStream_t stream)
{
    const int*   queries  = (const int*)  d_in[0];
    const int*   stories  = (const int*)  d_in[1];
    const float* q_bias   = (const float*)d_in[2];
    const float* st_bias  = (const float*)d_in[3];
    const float* mem_bias = (const float*)d_in[4];
    const float* out_bias = (const float*)d_in[5];
    const float* w_int    = (const float*)d_in[6];
    const float* w_out    = (const float*)d_in[7];
    const float* w_final  = (const float*)d_in[8];
    float* out = (float*)d_out;

    // ws layout (floats): memory | output | numer | denom | q2
    float* memory = (float*)d_ws;
    float* output = memory + (size_t)kB * kM * kE;        // 1,048,576
    float* numer  = output + (size_t)kB * kM * kE;        // 1,048,576
    float* denom  = numer  + 3 * kB * 4 * kE;             // 24,576
    float* q2     = denom  + 3 * kB * 4;                  // 192
    // q2: kB*kE = 2,048 floats

    embed_stories_kernel<<<dim3((kB * kM) / 2), dim3(256), 0, stream>>>(
        stories, st_bias, out_bias, mem_bias, memory, output, denom);

    hops_final_kernel<<<dim3(64), dim3(1024), 0, stream>>>(
        queries, q_bias, memory, output, w_int, w_out, w_final,
        numer, denom, q2, out);
}

// Round 6
// 173.598 us; speedup vs baseline: 1.1314x; 1.0262x over previous
//
#include <hip/hip_runtime.h>

constexpr int kB    = 16;
constexpr int kM    = 512;
constexpr int kS    = 32;
constexpr int kE    = 128;
constexpr int kV    = 32000;
constexpr int kVN   = kV - 1;   // nil (zero) row index
constexpr int kMS   = 132;      // padded LDS stride for hops mem tile

// -------------------------------------------------------------------------
// Kernel 1: story embeddings (R6-proven, untouched). 2 rows per 256-thread
// block, grid = 4096. Streams 268 MB of 512B gather traffic at the
// memory-system rate (~6.6 TB/s) -> ~40.5 µs structural floor.
// enc[s][e] = 1 + (e-63)(s-15)/1024 (exact f32 match of numpy formula).
// Block 0 zeroes bar[0..31]: 16 per-b hop counters + 16 relu-x ready flags.
// -------------------------------------------------------------------------
__global__ __launch_bounds__(256) void embed_stories_kernel(
    const int*   __restrict__ stories,   // [B,M,S]
    const float* __restrict__ st_bias,   // [VN,E]
    const float* __restrict__ out_bias,  // [VN,E]
    const float* __restrict__ mem_bias,  // [M,E]
    float*       __restrict__ memory,    // [B,M,E]
    float*       __restrict__ output,    // [B,M,E]
    unsigned*    __restrict__ bar)       // [32] counters/flags -> zeroed
{
    __shared__ int sidx[2][kS];
    __shared__ __align__(16) float pm[8][kE];
    __shared__ __align__(16) float po[8][kE];

    const int t    = threadIdx.x;
    const int row0 = blockIdx.x * 2;
    if (t < 64) sidx[t >> 5][t & 31] = stories[row0 * kS + t];
    if (blockIdx.x == 0 && t < 32) bar[t] = 0u;
    __syncthreads();

    const int g    = t >> 5;
    const int lane = t & 31;
    const int p    = g >> 2;       // row of pair
    const int ph   = g & 3;        // s-phase
    const int e0   = lane * 4;
    const float ef0 = (float)(e0 - 63), ef1 = (float)(e0 - 62);
    const float ef2 = (float)(e0 - 61), ef3 = (float)(e0 - 60);

    float4 am = {0.f, 0.f, 0.f, 0.f};
    float4 ao = {0.f, 0.f, 0.f, 0.f};
    #pragma unroll
    for (int j = 0; j < 8; ++j) {
        const int s   = ph * 8 + j;
        const int idx = sidx[p][s];
        const int ci  = idx < kVN ? idx : (kVN - 1);       // clamped row
        const float live = (idx < kVN) ? 1.0f : 0.0f;      // nil -> weight 0
        const float sf = (float)(s - 15) * (1.0f / 1024.0f);
        const float4 vm = *(const float4*)(st_bias  + (size_t)ci * kE + e0);
        const float4 vo = *(const float4*)(out_bias + (size_t)ci * kE + e0);
        const float c0 = fmaf(ef0, sf, 1.0f) * live;
        const float c1 = fmaf(ef1, sf, 1.0f) * live;
        const float c2 = fmaf(ef2, sf, 1.0f) * live;
        const float c3 = fmaf(ef3, sf, 1.0f) * live;
        am.x = fmaf(vm.x, c0, am.x); am.y = fmaf(vm.y, c1, am.y);
        am.z = fmaf(vm.z, c2, am.z); am.w = fmaf(vm.w, c3, am.w);
        ao.x = fmaf(vo.x, c0, ao.x); ao.y = fmaf(vo.y, c1, ao.y);
        ao.z = fmaf(vo.z, c2, ao.z); ao.w = fmaf(vo.w, c3, ao.w);
    }
    *(float4*)&pm[g][e0] = am;
    *(float4*)&po[g][e0] = ao;
    __syncthreads();

    const int pr = t >> 7;
    const int e  = t & 127;
    const int row = row0 + pr;
    const int m   = row & (kM - 1);
    const float sm = pm[pr * 4 + 0][e] + pm[pr * 4 + 1][e] +
                     pm[pr * 4 + 2][e] + pm[pr * 4 + 3][e];
    const float so = po[pr * 4 + 0][e] + po[pr * 4 + 1][e] +
                     po[pr * 4 + 2][e] + po[pr * 4 + 3][e];
    memory[(size_t)row * kE + e] = sm + mem_bias[m * kE + e];
    output[(size_t)row * kE + e] = so;
}

// -------------------------------------------------------------------------
// Fence-free 4-block spin barrier (R4/R6-proven) + agent-scope accessors.
// -------------------------------------------------------------------------
__device__ __forceinline__ void group_barrier(unsigned* ctr, unsigned target)
{
    __syncthreads();
    if (threadIdx.x == 0) {
        __hip_atomic_fetch_add(ctr, 1u, __ATOMIC_RELEASE, __HIP_MEMORY_SCOPE_AGENT);
        while (__hip_atomic_load(ctr, __ATOMIC_RELAXED, __HIP_MEMORY_SCOPE_AGENT) < target)
            __builtin_amdgcn_s_sleep(2);
    }
    __syncthreads();
}
__device__ __forceinline__ void cstore(float* p, float v) {
    __hip_atomic_store(p, v, __ATOMIC_RELAXED, __HIP_MEMORY_SCOPE_AGENT);
}
__device__ __forceinline__ float cload(const float* p) {
    return __hip_atomic_load(p, __ATOMIC_RELAXED, __HIP_MEMORY_SCOPE_AGENT);
}

// -------------------------------------------------------------------------
// Kernel 2 (R16 = R12 skeleton + surgical hop-2 change): 64 blocks x 1024
// threads, b = bid&15 (4 blocks/group, XCD-colocated), qtr = bid>>4,
// 128 rows/block, LDS-staged tiles, counter barriers for hops 0/1.
// Hop-2 delta vs R12: the all-64 counter barrier (64 serialized RMWs on
// one LLC line + grid-wide straggler wait) is replaced by 16 per-b
// producer flags: after the (proven) target-12 arrive, only qtr==0
// computes combine -> w_out -> relu (others skip the redundant pass),
// cstores sxg[b], drains, release-stores bar[16+b]. Consumers poll the
// 16 flags with 16 threads. Arithmetic is bit-identical to R12.
// -------------------------------------------------------------------------
__global__ __launch_bounds__(1024) void hops_final_kernel(
    const int*   __restrict__ queries,   // [B,S]
    const float* __restrict__ q_bias,    // [VN,E]
    const float* __restrict__ memory,    // [B,M,E]
    const float* __restrict__ output,    // [B,M,E]
    const float* __restrict__ w_int,     // [E,E]
    const float* __restrict__ w_out,     // [E,E]
    const float* __restrict__ wf,        // [E,V]
    float*       __restrict__ numer,     // [2,B,4,E]
    float*       __restrict__ denom,     // [2,B,4]
    float*                    sxg,       // [B,E] relu-x exchange
    unsigned*                 bar,       // [32]: [0..15] ctr, [16..31] flag
    float*       __restrict__ out)       // [B,V]
{
    __shared__ __align__(16) float mem_lds[128 * kMS];  // reused as sx in tail
    __shared__ __align__(16) float out_lds[128 * kE];   // reused as ps in tail
    __shared__ float sc_q[128];
    __shared__ __align__(16) float q_s[kE];
    __shared__ float xb[kE];
    __shared__ float dtmp;

    const int bid = blockIdx.x;
    const int b   = bid & 15;      // XCD-colocated groups (bids ≡ b mod 16)
    const int qtr = bid >> 4;
    const int t   = threadIdx.x;
    unsigned* ctr = bar + b;

    // ---- stage this quarter's 128 mem/out rows into LDS ----
    const float* memb = memory + ((size_t)b * kM + qtr * 128) * kE;
    const float* outb = output + ((size_t)b * kM + qtr * 128) * kE;
    #pragma unroll
    for (int i = 0; i < 4; ++i) {
        const int flat = t + i * 1024;
        const int rr = flat >> 5, ff = (flat & 31) * 4;
        *(float4*)&mem_lds[rr * kMS + ff] = *(const float4*)&memb[(size_t)rr * kE + ff];
        *(float4*)&out_lds[rr * kE  + ff] = *(const float4*)&outb[(size_t)rr * kE + ff];
    }

    // ---- q-embed: gathers issue concurrently with the staging above ----
    {
        __shared__ __align__(16) float part8q[8][kE];
        if (t < 256) {
            const int g = t >> 5, lane = t & 31, e0 = lane * 4;
            const float f0 = (float)(e0 - 63) * (1.0f / 1024.0f);
            const float f1 = (float)(e0 - 62) * (1.0f / 1024.0f);
            const float f2 = (float)(e0 - 61) * (1.0f / 1024.0f);
            const float f3 = (float)(e0 - 60) * (1.0f / 1024.0f);
            float4 a = {0.f, 0.f, 0.f, 0.f};
            #pragma unroll
            for (int j = 0; j < 4; ++j) {
                const int s   = g * 4 + j;
                const int idx = queries[b * kS + s];      // L1-hot, 2 KB table
                const int ci  = idx < kVN ? idx : (kVN - 1);
                const float live = (idx < kVN) ? 1.0f : 0.0f;
                const float sf = (float)(s - 15);
                const float4 v = *(const float4*)&q_bias[(size_t)ci * kE + e0];
                a.x = fmaf(v.x, fmaf(f0, sf, 1.f) * live, a.x);
                a.y = fmaf(v.y, fmaf(f1, sf, 1.f) * live, a.y);
                a.z = fmaf(v.z, fmaf(f2, sf, 1.f) * live, a.z);
                a.w = fmaf(v.w, fmaf(f3, sf, 1.f) * live, a.w);
            }
            *(float4*)&part8q[g][e0] = a;
        }
        __syncthreads();
        if (t < kE) {
            float s = 0.f;
            #pragma unroll
            for (int g = 0; g < 8; ++g) s += part8q[g][t];
            q_s[t] = s;
        }
        __syncthreads();
    }

    __shared__ __align__(16) float part8[8][kE];

    for (int hop = 0; hop < 3; ++hop) {
        // ---- scores for own 128 rows: 8 lanes x 16 e per row ----
        {
            const int rw = t >> 3, sub = t & 7;
            const float4* qv = (const float4*)&q_s[sub * 16];
            const float4* mv = (const float4*)&mem_lds[rw * kMS + sub * 16];
            float d = 0.f;
            #pragma unroll
            for (int i = 0; i < 4; ++i) {
                const float4 m4 = mv[i], q4 = qv[i];
                d = fmaf(m4.x, q4.x, d); d = fmaf(m4.y, q4.y, d);
                d = fmaf(m4.z, q4.z, d); d = fmaf(m4.w, q4.w, d);
            }
            d += __shfl_down(d, 4);
            d += __shfl_down(d, 2);
            d += __shfl_down(d, 1);
            if (sub == 0) sc_q[rw] = __expf(d);   // no max-sub: |s| = O(1)
        }
        __syncthreads();

        // ---- numer partial ----
        {
            const int grp = t >> 7, e = t & 127;
            float acc = 0.f;
            const float* pp = &sc_q[grp * 16];
            const float* ob = &out_lds[grp * 16 * kE + e];
            #pragma unroll
            for (int j = 0; j < 16; ++j)
                acc = fmaf(pp[j], ob[j * kE], acc);
            part8[grp][e] = acc;
        }
        __syncthreads();

        // ---- publish partials ----
        const int pb = hop & 1;
        float* nq = numer + (((size_t)pb * kB + b) * 4 + qtr) * kE;
        if (t < kE) {
            float s = 0.f;
            #pragma unroll
            for (int g = 0; g < 8; ++g) s += part8[g][t];
            cstore(&nq[t], s);
        } else if (t < 192) {
            const int l = t - 128;
            float s2 = sc_q[l] + sc_q[l + 64];
            #pragma unroll
            for (int off = 32; off; off >>= 1) s2 += __shfl_down(s2, off);
            if (l == 0) cstore(&denom[((size_t)pb * kB + b) * 4 + qtr], s2);
        }

        if (hop < 2) {
            group_barrier(ctr, 4u * (hop + 1));

            // ---- combine: xb = q + sum(numer)/sum(denom) ----
            if (t < kE) {
                const float* nn = numer + ((size_t)pb * kB + b) * 4 * kE;
                const float* dd = denom + ((size_t)pb * kB + b) * 4;
                const float ns = cload(&nn[t]) + cload(&nn[kE + t]) +
                                 cload(&nn[2 * kE + t]) + cload(&nn[3 * kE + t]);
                const float ds = cload(&dd[0]) + cload(&dd[1]) +
                                 cload(&dd[2]) + cload(&dd[3]);
                xb[t] = q_s[t] + ns / ds;
            }
            __syncthreads();

            // ---- q' = xb @ w_int (8 k-groups of 16) ----
            {
                const int grp = t >> 7, e = t & 127;
                float acc = 0.f;
                #pragma unroll
                for (int j = 0; j < 16; ++j) {
                    const int k = grp * 16 + j;
                    acc = fmaf(xb[k], w_int[k * kE + e], acc);
                }
                part8[grp][e] = acc;
            }
            __syncthreads();
            if (t < kE) {
                float s = 0.f;
                #pragma unroll
                for (int g = 0; g < 8; ++g) s += part8[g][t];
                q_s[t] = s;
            }
            __syncthreads();
        } else {
            // ---- hop 2: arrive (counter, proven pattern); only qtr 0
            //      waits for the 4 partials and produces relu-x ----
            __syncthreads();   // drains this block's numer/denom cstores
            if (t == 0)
                __hip_atomic_fetch_add(ctr, 1u, __ATOMIC_RELEASE,
                                       __HIP_MEMORY_SCOPE_AGENT);
            if (qtr == 0) {
                if (t == 0) {
                    while (__hip_atomic_load(ctr, __ATOMIC_RELAXED,
                                             __HIP_MEMORY_SCOPE_AGENT) < 12u)
                        __builtin_amdgcn_s_sleep(2);
                }
                __syncthreads();
                if (t < kE) {
                    const float* nn = numer + ((size_t)pb * kB + b) * 4 * kE;
                    const float* dd = denom + ((size_t)pb * kB + b) * 4;
                    const float ns = cload(&nn[t]) + cload(&nn[kE + t]) +
                                     cload(&nn[2 * kE + t]) + cload(&nn[3 * kE + t]);
                    const float ds = cload(&dd[0]) + cload(&dd[1]) +
                                     cload(&dd[2]) + cload(&dd[3]);
                    xb[t] = q_s[t] + ns / ds;
                }
                __syncthreads();
                {
                    const int grp = t >> 7, e = t & 127;
                    float acc = 0.f;
                    #pragma unroll
                    for (int j = 0; j < 16; ++j) {
                        const int k = grp * 16 + j;
                        acc = fmaf(xb[k], w_out[k * kE + e], acc);
                    }
                    part8[grp][e] = acc;
                }
                __syncthreads();
                if (t < kE) {
                    float s = 0.f;
                    #pragma unroll
                    for (int g = 0; g < 8; ++g) s += part8[g][t];
                    cstore(&sxg[b * kE + t], fmaxf(s, 0.f));
                }
                __syncthreads();   // drain sxg cstores
                if (t == 0)
                    __hip_atomic_store(&bar[16 + b], 1u, __ATOMIC_RELEASE,
                                       __HIP_MEMORY_SCOPE_AGENT);
            }
        }
    }

    // ---- wait for all 16 relu-x vectors (16 pollers per block) ----
    if (t < 16) {
        while (__hip_atomic_load(&bar[16 + t], __ATOMIC_RELAXED,
                                 __HIP_MEMORY_SCOPE_AGENT) == 0u)
            __builtin_amdgcn_s_sleep(2);
    }
    __syncthreads();

    // ---- stage sxg into LDS (8 KB, linear [b][e]) ----
    float* sx = mem_lds;                        // safe reuse after hops
    if (t < 512) {
        *(float4*)&sx[t * 4] = *(const float4*)&sxg[t * 4];
    }
    __syncthreads();

    // ---- fused final: out[b, v] = relu_x[b,:] . wf[:, v] ----
    // 500 v-columns per block (64 x 500 = 32000); 512 v-lanes x 2 e-halves;
    // halves combined via LDS ps[b][vt] (stride-1). Only global loads in
    // the loop are the coalesced wf stream; sx reads are LDS broadcasts.
    {
        const int vt = t & 511;
        const int h  = t >> 9;
        const int v  = bid * 500 + vt;
        float* ps = out_lds;                    // reuse: 16*512*4 = 32 KB
        float acc[kB];
        #pragma unroll
        for (int b2 = 0; b2 < kB; ++b2) acc[b2] = 0.f;

        if (vt < 500) {
            const int e0 = h * 64;
            #pragma unroll 8
            for (int ei = 0; ei < 64; ++ei) {
                const int e = e0 + ei;
                const float wv = wf[(size_t)e * kV + v];
                #pragma unroll
                for (int b2 = 0; b2 < kB; ++b2)
                    acc[b2] = fmaf(sx[b2 * kE + e], wv, acc[b2]);
            }
            if (h == 1) {
                #pragma unroll
                for (int b2 = 0; b2 < kB; ++b2) ps[b2 * 512 + vt] = acc[b2];
            }
        }
        __syncthreads();
        if (h == 0 && vt < 500) {
            #pragma unroll
            for (int b2 = 0; b2 < kB; ++b2)
                out[(size_t)b2 * kV + v] = acc[b2] + ps[b2 * 512 + vt];
        }
    }
}

// -------------------------------------------------------------------------
extern "C" void kernel_launch(void* const* d_in, const int* in_sizes, int n_in,
                              void* d_out, int out_size, void* d_ws, size_t ws_size,
                              hipStream_t stream)
{
    const int*   queries  = (const int*)  d_in[0];
    const int*   stories  = (const int*)  d_in[1];
    const float* q_bias   = (const float*)d_in[2];
    const float* st_bias  = (const float*)d_in[3];
    const float* mem_bias = (const float*)d_in[4];
    const float* out_bias = (const float*)d_in[5];
    const float* w_int    = (const float*)d_in[6];
    const float* w_out    = (const float*)d_in[7];
    const float* w_final  = (const float*)d_in[8];
    float* out = (float*)d_out;

    // ws layout (floats): memory | output | numer | denom | sxg | bar
    float* memory = (float*)d_ws;
    float* output = memory + (size_t)kB * kM * kE;        // 1,048,576
    float* numer  = output + (size_t)kB * kM * kE;        // 1,048,576
    float* denom  = numer  + 2 * kB * 4 * kE;             // 16,384
    float* sxg    = denom  + 2 * kB * 4;                  // 128
    unsigned* bar = (unsigned*)(sxg + kB * kE);           // 2,048

    embed_stories_kernel<<<dim3((kB * kM) / 2), dim3(256), 0, stream>>>(
        stories, st_bias, out_bias, mem_bias, memory, output, bar);

    hops_final_kernel<<<dim3(64), dim3(1024), 0, stream>>>(
        queries, q_bias, memory, output, w_int, w_out, w_final,
        numer, denom, sxg, bar, out);
}

// Round 7
// 169.497 us; speedup vs baseline: 1.1588x; 1.0242x over previous
//
#include <hip/hip_runtime.h>

constexpr int kB  = 16;
constexpr int kM  = 512;
constexpr int kS  = 32;
constexpr int kE  = 128;
constexpr int kV  = 32000;
constexpr int kVN = kV - 1;   // nil (zero) row index
constexpr int kMS = 132;      // padded LDS stride for hops mem tile

// -------------------------------------------------------------------------
// Kernel 1: story embeddings (R6-proven). R17 adds a wf LLC-prefetch: one
// guarded float4 of w_final per thread (4096 blocks x 256 x 16 B covers all
// 16.4 MB; every 64B line touched), value kept alive by an asm sink. Embed
// is fabric-bound on LLC gather hits; the HBM read path is idle, so warming
// wf (evicted every iteration by the 268 MB workspace poison fill) is free
// here and converts the tail's wf reads from HBM- to LLC-latency.
// Block 0 zeroes bar[0..16]: 16 per-b hop counters + 1 all-64 counter.
// -------------------------------------------------------------------------
__global__ __launch_bounds__(256) void embed_stories_kernel(
    const int*   __restrict__ stories,   // [B,M,S]
    const float* __restrict__ st_bias,   // [VN,E]
    const float* __restrict__ out_bias,  // [VN,E]
    const float* __restrict__ mem_bias,  // [M,E]
    const float* __restrict__ wf,        // [E,V] (prefetch only)
    float*       __restrict__ memory,    // [B,M,E]
    float*       __restrict__ output,    // [B,M,E]
    unsigned*    __restrict__ bar)       // [B+1] counters -> zeroed by block 0
{
    __shared__ int sidx[2][kS];
    __shared__ __align__(16) float pm[8][kE];
    __shared__ __align__(16) float po[8][kE];

    const int t    = threadIdx.x;
    const int row0 = blockIdx.x * 2;

    // ---- wf LLC-prefetch: issue first, sink at the end (zero stall) ----
    const size_t pfo = ((size_t)blockIdx.x * 256 + t) * 4;  // float offset
    float4 pf4 = {0.f, 0.f, 0.f, 0.f};
    if (pfo < (size_t)kE * kV) pf4 = *(const float4*)(wf + pfo);

    if (t < 64) sidx[t >> 5][t & 31] = stories[row0 * kS + t];
    if (blockIdx.x == 0 && t < kB + 1) bar[t] = 0u;
    __syncthreads();

    const int g    = t >> 5;
    const int lane = t & 31;
    const int p    = g >> 2;       // row of pair
    const int ph   = g & 3;        // s-phase
    const int e0   = lane * 4;
    const float ef0 = (float)(e0 - 63), ef1 = (float)(e0 - 62);
    const float ef2 = (float)(e0 - 61), ef3 = (float)(e0 - 60);

    float4 am = {0.f, 0.f, 0.f, 0.f};
    float4 ao = {0.f, 0.f, 0.f, 0.f};
    #pragma unroll
    for (int j = 0; j < 8; ++j) {
        const int s   = ph * 8 + j;
        const int idx = sidx[p][s];
        const int ci  = idx < kVN ? idx : (kVN - 1);       // clamped row
        const float live = (idx < kVN) ? 1.0f : 0.0f;      // nil -> weight 0
        const float sf = (float)(s - 15) * (1.0f / 1024.0f);
        const float4 vm = *(const float4*)(st_bias  + (size_t)ci * kE + e0);
        const float4 vo = *(const float4*)(out_bias + (size_t)ci * kE + e0);
        const float c0 = fmaf(ef0, sf, 1.0f) * live;
        const float c1 = fmaf(ef1, sf, 1.0f) * live;
        const float c2 = fmaf(ef2, sf, 1.0f) * live;
        const float c3 = fmaf(ef3, sf, 1.0f) * live;
        am.x = fmaf(vm.x, c0, am.x); am.y = fmaf(vm.y, c1, am.y);
        am.z = fmaf(vm.z, c2, am.z); am.w = fmaf(vm.w, c3, am.w);
        ao.x = fmaf(vo.x, c0, ao.x); ao.y = fmaf(vo.y, c1, ao.y);
        ao.z = fmaf(vo.z, c2, ao.z); ao.w = fmaf(vo.w, c3, ao.w);
    }
    *(float4*)&pm[g][e0] = am;
    *(float4*)&po[g][e0] = ao;

    // keep the prefetch load alive (no DCE), data discarded
    asm volatile("" :: "v"(pf4.x));
    __syncthreads();

    const int pr = t >> 7;
    const int e  = t & 127;
    const int row = row0 + pr;
    const int m   = row & (kM - 1);
    const float sm = pm[pr * 4 + 0][e] + pm[pr * 4 + 1][e] +
                     pm[pr * 4 + 2][e] + pm[pr * 4 + 3][e];
    const float so = po[pr * 4 + 0][e] + po[pr * 4 + 1][e] +
                     po[pr * 4 + 2][e] + po[pr * 4 + 3][e];
    memory[(size_t)row * kE + e] = sm + mem_bias[m * kE + e];
    output[(size_t)row * kE + e] = so;
}

// -------------------------------------------------------------------------
// Fence-free 4-block spin barrier (R4/R6-proven). Cross-block data via
// agent-scope RELAXED atomics (no cache-maintenance storms — R3 lesson).
// -------------------------------------------------------------------------
__device__ __forceinline__ void group_barrier(unsigned* ctr, unsigned target)
{
    __syncthreads();
    if (threadIdx.x == 0) {
        __hip_atomic_fetch_add(ctr, 1u, __ATOMIC_RELEASE, __HIP_MEMORY_SCOPE_AGENT);
        while (__hip_atomic_load(ctr, __ATOMIC_RELAXED, __HIP_MEMORY_SCOPE_AGENT) < target)
            __builtin_amdgcn_s_sleep(2);
    }
    __syncthreads();
}
__device__ __forceinline__ void cstore(float* p, float v) {
    __hip_atomic_store(p, v, __ATOMIC_RELAXED, __HIP_MEMORY_SCOPE_AGENT);
}
__device__ __forceinline__ float cload(const float* p) {
    return __hip_atomic_load(p, __ATOMIC_RELAXED, __HIP_MEMORY_SCOPE_AGENT);
}

// -------------------------------------------------------------------------
// Kernel 2 (R17 = R12 VERBATIM + wf L2-prefetch). 64 blocks x 1024 threads,
// b = bid&15 (4 blocks/group, XCD-colocated — R10), qtr = bid>>4. Counter
// barriers for all 3 hops + all-64 barrier before the fused tail (the
// measured optimum of the sync design space: R13 16-wide fan-in = 44 µs,
// R14 no-sync 16-block = 53 µs, R15/R16 flag chains = 50-62 µs, R12 < 40).
// New: 4 strided float4 touches/thread (4096 x 64B lines = the block's
// 256 KB wf tail slice) issued with the staging loads, asm-sunk — warms
// the XCD L2 so the tail's wf loads are ~200-500cy instead of ~900cy HBM.
// -------------------------------------------------------------------------
__global__ __launch_bounds__(1024) void hops_final_kernel(
    const int*   __restrict__ queries,   // [B,S]
    const float* __restrict__ q_bias,    // [VN,E]
    const float* __restrict__ memory,    // [B,M,E]
    const float* __restrict__ output,    // [B,M,E]
    const float* __restrict__ w_int,     // [E,E]
    const float* __restrict__ w_out,     // [E,E]
    const float* __restrict__ wf,        // [E,V]
    float*       __restrict__ numer,     // [2,B,4,E]
    float*       __restrict__ denom,     // [2,B,4]
    float*                    xg,        // [E,B] transposed relu_x exchange
    unsigned*    __restrict__ bar,       // [B+1] counters (zeroed by embed)
    float*       __restrict__ out)       // [B,V]
{
    __shared__ __align__(16) float mem_lds[128 * kMS];  // reused as sx in tail
    __shared__ __align__(16) float out_lds[128 * kE];   // reused as ps in tail
    __shared__ float sc_q[128];
    __shared__ __align__(16) float q_s[kE];
    __shared__ float xb[kE];
    __shared__ __align__(16) float part8[8][kE];

    const int bid = blockIdx.x;
    const int b   = bid & 15;      // XCD-colocated groups (R10)
    const int qtr = bid >> 4;
    const int t   = threadIdx.x;
    unsigned* ctr = bar + b;

    // ---- stage this quarter's 128 mem/out rows into LDS ----
    const float* memb = memory + ((size_t)b * kM + qtr * 128) * kE;
    const float* outb = output + ((size_t)b * kM + qtr * 128) * kE;
    #pragma unroll
    for (int i = 0; i < 4; ++i) {
        const int flat = t + i * 1024;
        const int rr = flat >> 5, ff = (flat & 31) * 4;
        *(float4*)&mem_lds[rr * kMS + ff] = *(const float4*)&memb[(size_t)rr * kE + ff];
        *(float4*)&out_lds[rr * kE  + ff] = *(const float4*)&outb[(size_t)rr * kE + ff];
    }

    // ---- wf L2-prefetch: 4 line-touches per thread (i = t + j*1024 ->
    //      e = i>>5, k16 = i&31 -> 64B line of this block's 500-col slice).
    //      Drained by the first __syncthreads; data discarded via sink. ----
    float4 pf0, pf1, pf2, pf3;
    {
        const int i0 = t;
        pf0 = *(const float4*)(wf + (size_t)(i0 >> 5) * kV + bid * 500 + (i0 & 31) * 16);
        const int i1 = t + 1024;
        pf1 = *(const float4*)(wf + (size_t)(i1 >> 5) * kV + bid * 500 + (i1 & 31) * 16);
        const int i2 = t + 2048;
        pf2 = *(const float4*)(wf + (size_t)(i2 >> 5) * kV + bid * 500 + (i2 & 31) * 16);
        const int i3 = t + 3072;
        pf3 = *(const float4*)(wf + (size_t)(i3 >> 5) * kV + bid * 500 + (i3 & 31) * 16);
    }

    // ---- q-embed: gathers issue concurrently with the staging above ----
    if (t < 256) {
        const int g = t >> 5, lane = t & 31, e0 = lane * 4;
        const float f0 = (float)(e0 - 63) * (1.0f / 1024.0f);
        const float f1 = (float)(e0 - 62) * (1.0f / 1024.0f);
        const float f2 = (float)(e0 - 61) * (1.0f / 1024.0f);
        const float f3 = (float)(e0 - 60) * (1.0f / 1024.0f);
        float4 a = {0.f, 0.f, 0.f, 0.f};
        #pragma unroll
        for (int j = 0; j < 4; ++j) {
            const int s   = g * 4 + j;
            const int idx = queries[b * kS + s];          // L1-hot, 2 KB table
            const int ci  = idx < kVN ? idx : (kVN - 1);
            const float live = (idx < kVN) ? 1.0f : 0.0f;
            const float sf = (float)(s - 15);
            const float4 v = *(const float4*)&q_bias[(size_t)ci * kE + e0];
            a.x = fmaf(v.x, fmaf(f0, sf, 1.f) * live, a.x);
            a.y = fmaf(v.y, fmaf(f1, sf, 1.f) * live, a.y);
            a.z = fmaf(v.z, fmaf(f2, sf, 1.f) * live, a.z);
            a.w = fmaf(v.w, fmaf(f3, sf, 1.f) * live, a.w);
        }
        *(float4*)&part8[g][e0] = a;
    }
    // keep the prefetch loads alive (no DCE), data discarded
    asm volatile("" :: "v"(pf0.x), "v"(pf1.x), "v"(pf2.x), "v"(pf3.x));
    __syncthreads();
    if (t < kE) {
        float s = 0.f;
        #pragma unroll
        for (int g = 0; g < 8; ++g) s += part8[g][t];
        q_s[t] = s;
    }
    __syncthreads();

    const int grp = t >> 7;
    const int e   = t & 127;

    for (int hop = 0; hop < 3; ++hop) {
        // ---- scores for own 128 rows: 8 lanes x 16 e per row ----
        {
            const int rw = t >> 3, sub = t & 7;
            const float4* qv = (const float4*)&q_s[sub * 16];
            const float4* mv = (const float4*)&mem_lds[rw * kMS + sub * 16];
            float d = 0.f;
            #pragma unroll
            for (int i = 0; i < 4; ++i) {
                const float4 m4 = mv[i], q4 = qv[i];
                d = fmaf(m4.x, q4.x, d); d = fmaf(m4.y, q4.y, d);
                d = fmaf(m4.z, q4.z, d); d = fmaf(m4.w, q4.w, d);
            }
            d += __shfl_down(d, 4);
            d += __shfl_down(d, 2);
            d += __shfl_down(d, 1);
            if (sub == 0) sc_q[rw] = __expf(d);   // no max-sub: |s| = O(1)
        }
        __syncthreads();

        // ---- numer partial ----
        {
            float acc = 0.f;
            const float* pp = &sc_q[grp * 16];
            const float* ob = &out_lds[grp * 16 * kE + e];
            #pragma unroll
            for (int j = 0; j < 16; ++j)
                acc = fmaf(pp[j], ob[j * kE], acc);
            part8[grp][e] = acc;
        }
        __syncthreads();

        const int pb = hop & 1;
        float* nq = numer + (((size_t)pb * kB + b) * 4 + qtr) * kE;
        if (t < kE) {
            float s = 0.f;
            #pragma unroll
            for (int g = 0; g < 8; ++g) s += part8[g][t];
            cstore(&nq[t], s);
        } else if (t < 192) {
            const int l = t - 128;
            float s2 = sc_q[l] + sc_q[l + 64];
            #pragma unroll
            for (int off = 32; off; off >>= 1) s2 += __shfl_down(s2, off);
            if (l == 0) cstore(&denom[((size_t)pb * kB + b) * 4 + qtr], s2);
        }

        group_barrier(ctr, 4u * (hop + 1));

        // ---- combine: xb = q + sum(numer)/sum(denom) ----
        if (t < kE) {
            const float* nn = numer + ((size_t)pb * kB + b) * 4 * kE;
            const float* dd = denom + ((size_t)pb * kB + b) * 4;
            const float ns = cload(&nn[t]) + cload(&nn[kE + t]) +
                             cload(&nn[2 * kE + t]) + cload(&nn[3 * kE + t]);
            const float ds = cload(&dd[0]) + cload(&dd[1]) +
                             cload(&dd[2]) + cload(&dd[3]);
            xb[t] = q_s[t] + ns / ds;
        }
        __syncthreads();

        // ---- q' = xb @ W (redundant, 8 k-groups of 16) ----
        {
            const float* w = (hop == 2) ? w_out : w_int;
            float acc = 0.f;
            #pragma unroll
            for (int j = 0; j < 16; ++j) {
                const int k = grp * 16 + j;
                acc = fmaf(xb[k], w[k * kE + e], acc);
            }
            part8[grp][e] = acc;
        }
        __syncthreads();
        if (t < kE) {
            float s = 0.f;
            #pragma unroll
            for (int g = 0; g < 8; ++g) s += part8[g][t];
            q_s[t] = s;
        }
        __syncthreads();
    }

    // ---- exchange relu_x: cstore -> LLC; all-64 barrier; consumers'
    //      caches never touched xg lines -> loads fill fresh from LLC ----
    if (qtr == 0 && t < kE) cstore(&xg[t * kB + b], fmaxf(q_s[t], 0.f));
    group_barrier(bar + kB, 64u);

    // ---- stage xg into LDS (8 KB): sx[e*16 + b] ----
    float* sx = mem_lds;                        // safe reuse after hops
    if (t < 512) {
        const float4 v4 = *(const float4*)&xg[t * 4];
        *(float4*)&sx[t * 4] = v4;
    }
    __syncthreads();

    // ---- fused final: out[b, v] = relu_x[b,:] . wf[:, v] ----
    // 500 v-columns per block (64 x 500 = 32000 exactly); 512 v-lanes x
    // 2 e-halves; halves combined via LDS ps[b][vt] (stride-1). The only
    // global loads in the loop are the wf stream (now L2/LLC-warm via the
    // prefetches); xg reads are LDS broadcasts.
    {
        const int vt = t & 511;
        const int h  = t >> 9;
        const int v  = bid * 500 + vt;
        float* ps = out_lds;                    // reuse: 16*512*4 = 32 KB
        float acc[kB];
        #pragma unroll
        for (int b2 = 0; b2 < kB; ++b2) acc[b2] = 0.f;

        if (vt < 500) {
            const int e0 = h * 64;
            #pragma unroll 8
            for (int ei = 0; ei < 64; ++ei) {
                const int ee = e0 + ei;
                const float wv = wf[(size_t)ee * kV + v];
                const float* xr = &sx[ee * kB]; // uniform addr -> broadcast
                #pragma unroll
                for (int b2 = 0; b2 < kB; ++b2)
                    acc[b2] = fmaf(xr[b2], wv, acc[b2]);
            }
            if (h == 1) {
                #pragma unroll
                for (int b2 = 0; b2 < kB; ++b2) ps[b2 * 512 + vt] = acc[b2];
            }
        }
        __syncthreads();
        if (h == 0 && vt < 500) {
            #pragma unroll
            for (int b2 = 0; b2 < kB; ++b2)
                out[(size_t)b2 * kV + v] = acc[b2] + ps[b2 * 512 + vt];
        }
    }
}

// -------------------------------------------------------------------------
extern "C" void kernel_launch(void* const* d_in, const int* in_sizes, int n_in,
                              void* d_out, int out_size, void* d_ws, size_t ws_size,
                              hipStream_t stream)
{
    const int*   queries  = (const int*)  d_in[0];
    const int*   stories  = (const int*)  d_in[1];
    const float* q_bias   = (const float*)d_in[2];
    const float* st_bias  = (const float*)d_in[3];
    const float* mem_bias = (const float*)d_in[4];
    const float* out_bias = (const float*)d_in[5];
    const float* w_int    = (const float*)d_in[6];
    const float* w_out    = (const float*)d_in[7];
    const float* w_final  = (const float*)d_in[8];
    float* out = (float*)d_out;

    // ws layout (floats): memory | output | numer | denom | xg | bar
    float* memory = (float*)d_ws;
    float* output = memory + (size_t)kB * kM * kE;        // 1,048,576
    float* numer  = output + (size_t)kB * kM * kE;        // 1,048,576
    float* denom  = numer  + 2 * kB * 4 * kE;             // 16,384
    float* xg     = denom  + 2 * kB * 4;                  // 128
    unsigned* bar = (unsigned*)(xg + kE * kB);            // 2,048

    embed_stories_kernel<<<dim3((kB * kM) / 2), dim3(256), 0, stream>>>(
        stories, st_bias, out_bias, mem_bias, w_final, memory, output, bar);

    hops_final_kernel<<<dim3(64), dim3(1024), 0, stream>>>(
        queries, q_bias, memory, output, w_int, w_out, w_final,
        numer, denom, xg, bar, out);
}

// Round 9
// 167.020 us; speedup vs baseline: 1.1759x; 1.0148x over previous
//
#include <hip/hip_runtime.h>

constexpr int kB  = 16;
constexpr int kM  = 512;
constexpr int kS  = 32;
constexpr int kE  = 128;
constexpr int kV  = 32000;
constexpr int kVN = kV - 1;   // nil (zero) row index
constexpr int kMS = 132;      // padded LDS stride for hops mem tile

// -------------------------------------------------------------------------
// Kernel 1: story embeddings (R6-proven). R18 keeps R17's wf LLC-prefetch
// (measured FREE: embed 40.92 µs with it, identical to without): one
// guarded float4 of w_final per thread (4096 x 256 x 16 B covers all
// 16.4 MB), asm-sunk. The workspace poison fill evicts the whole LLC every
// iteration; warming wf here converts the fused tail's wf stream from
// HBM-cold (~900 cy) to LLC-warm. Embed itself is fabric-bound on the
// 268 MB table-gather stream (FETCH 125 MB @ 3.3 TB/s beyond-L2, R17).
// Block 0 zeroes bar[0..16]: 16 per-b hop counters + 1 all-64 counter.
// -------------------------------------------------------------------------
__global__ __launch_bounds__(256) void embed_stories_kernel(
    const int*   __restrict__ stories,   // [B,M,S]
    const float* __restrict__ st_bias,   // [VN,E]
    const float* __restrict__ out_bias,  // [VN,E]
    const float* __restrict__ mem_bias,  // [M,E]
    const float* __restrict__ wf,        // [E,V] (prefetch only)
    float*       __restrict__ memory,    // [B,M,E]
    float*       __restrict__ output,    // [B,M,E]
    unsigned*    __restrict__ bar)       // [B+1] counters -> zeroed by block 0
{
    __shared__ int sidx[2][kS];
    __shared__ __align__(16) float pm[8][kE];
    __shared__ __align__(16) float po[8][kE];

    const int t    = threadIdx.x;
    const int row0 = blockIdx.x * 2;

    // ---- wf LLC-prefetch: issue first, sink at the end (zero stall) ----
    const size_t pfo = ((size_t)blockIdx.x * 256 + t) * 4;  // float offset
    float4 pf4 = {0.f, 0.f, 0.f, 0.f};
    if (pfo < (size_t)kE * kV) pf4 = *(const float4*)(wf + pfo);

    if (t < 64) sidx[t >> 5][t & 31] = stories[row0 * kS + t];
    if (blockIdx.x == 0 && t < kB + 1) bar[t] = 0u;
    __syncthreads();

    const int g    = t >> 5;
    const int lane = t & 31;
    const int p    = g >> 2;       // row of pair
    const int ph   = g & 3;        // s-phase
    const int e0   = lane * 4;
    const float ef0 = (float)(e0 - 63), ef1 = (float)(e0 - 62);
    const float ef2 = (float)(e0 - 61), ef3 = (float)(e0 - 60);

    float4 am = {0.f, 0.f, 0.f, 0.f};
    float4 ao = {0.f, 0.f, 0.f, 0.f};
    #pragma unroll
    for (int j = 0; j < 8; ++j) {
        const int s   = ph * 8 + j;
        const int idx = sidx[p][s];
        const int ci  = idx < kVN ? idx : (kVN - 1);       // clamped row
        const float live = (idx < kVN) ? 1.0f : 0.0f;      // nil -> weight 0
        const float sf = (float)(s - 15) * (1.0f / 1024.0f);
        const float4 vm = *(const float4*)(st_bias  + (size_t)ci * kE + e0);
        const float4 vo = *(const float4*)(out_bias + (size_t)ci * kE + e0);
        const float c0 = fmaf(ef0, sf, 1.0f) * live;
        const float c1 = fmaf(ef1, sf, 1.0f) * live;
        const float c2 = fmaf(ef2, sf, 1.0f) * live;
        const float c3 = fmaf(ef3, sf, 1.0f) * live;
        am.x = fmaf(vm.x, c0, am.x); am.y = fmaf(vm.y, c1, am.y);
        am.z = fmaf(vm.z, c2, am.z); am.w = fmaf(vm.w, c3, am.w);
        ao.x = fmaf(vo.x, c0, ao.x); ao.y = fmaf(vo.y, c1, ao.y);
        ao.z = fmaf(vo.z, c2, ao.z); ao.w = fmaf(vo.w, c3, ao.w);
    }
    *(float4*)&pm[g][e0] = am;
    *(float4*)&po[g][e0] = ao;

    // keep the prefetch load alive (no DCE), data discarded
    asm volatile("" :: "v"(pf4.x));
    __syncthreads();

    const int pr = t >> 7;
    const int e  = t & 127;
    const int row = row0 + pr;
    const int m   = row & (kM - 1);
    const float sm = pm[pr * 4 + 0][e] + pm[pr * 4 + 1][e] +
                     pm[pr * 4 + 2][e] + pm[pr * 4 + 3][e];
    const float so = po[pr * 4 + 0][e] + po[pr * 4 + 1][e] +
                     po[pr * 4 + 2][e] + po[pr * 4 + 3][e];
    memory[(size_t)row * kE + e] = sm + mem_bias[m * kE + e];
    output[(size_t)row * kE + e] = so;
}

// -------------------------------------------------------------------------
// Fence-free 4-block spin barrier (R4/R6-proven). Cross-block data via
// agent-scope RELAXED atomics (no cache-maintenance storms — R3 lesson).
// -------------------------------------------------------------------------
__device__ __forceinline__ void group_barrier(unsigned* ctr, unsigned target)
{
    __syncthreads();
    if (threadIdx.x == 0) {
        __hip_atomic_fetch_add(ctr, 1u, __ATOMIC_RELEASE, __HIP_MEMORY_SCOPE_AGENT);
        while (__hip_atomic_load(ctr, __ATOMIC_RELAXED, __HIP_MEMORY_SCOPE_AGENT) < target)
            __builtin_amdgcn_s_sleep(2);
    }
    __syncthreads();
}
__device__ __forceinline__ void cstore(float* p, float v) {
    __hip_atomic_store(p, v, __ATOMIC_RELAXED, __HIP_MEMORY_SCOPE_AGENT);
}
__device__ __forceinline__ float cload(const float* p) {
    return __hip_atomic_load(p, __ATOMIC_RELAXED, __HIP_MEMORY_SCOPE_AGENT);
}

// -------------------------------------------------------------------------
// Kernel 2 (R18 = R12 VERBATIM — the measured optimum of the sync design
// space: R13 16-wide fan-in = 44 µs, R14 no-sync 16-block = 53 µs,
// R15/R16 flag chains = 50-62 µs, R17 hops-side prefetch = +8 µs, R12 <40).
// 64 blocks x 1024 threads, b = bid&15 (4 blocks/group, XCD-colocated),
// qtr = bid>>4. No in-kernel prefetch: the tail's wf stream relies on the
// embed-side LLC warm (nothing between embed and the tail evicts 16 MB
// from the 256 MB LLC).
// -------------------------------------------------------------------------
__global__ __launch_bounds__(1024) void hops_final_kernel(
    const int*   __restrict__ queries,   // [B,S]
    const float* __restrict__ q_bias,    // [VN,E]
    const float* __restrict__ memory,    // [B,M,E]
    const float* __restrict__ output,    // [B,M,E]
    const float* __restrict__ w_int,     // [E,E]
    const float* __restrict__ w_out,     // [E,E]
    const float* __restrict__ wf,        // [E,V]
    float*       __restrict__ numer,     // [2,B,4,E]
    float*       __restrict__ denom,     // [2,B,4]
    float*                    xg,        // [E,B] transposed relu_x exchange
    unsigned*    __restrict__ bar,       // [B+1] counters (zeroed by embed)
    float*       __restrict__ out)       // [B,V]
{
    __shared__ __align__(16) float mem_lds[128 * kMS];  // reused as sx in tail
    __shared__ __align__(16) float out_lds[128 * kE];   // reused as ps in tail
    __shared__ float sc_q[128];
    __shared__ __align__(16) float q_s[kE];
    __shared__ float xb[kE];
    __shared__ __align__(16) float part8[8][kE];

    const int bid = blockIdx.x;
    const int b   = bid & 15;      // XCD-colocated groups (R10)
    const int qtr = bid >> 4;
    const int t   = threadIdx.x;
    unsigned* ctr = bar + b;

    // ---- stage this quarter's 128 mem/out rows into LDS ----
    const float* memb = memory + ((size_t)b * kM + qtr * 128) * kE;
    const float* outb = output + ((size_t)b * kM + qtr * 128) * kE;
    #pragma unroll
    for (int i = 0; i < 4; ++i) {
        const int flat = t + i * 1024;
        const int rr = flat >> 5, ff = (flat & 31) * 4;
        *(float4*)&mem_lds[rr * kMS + ff] = *(const float4*)&memb[(size_t)rr * kE + ff];
        *(float4*)&out_lds[rr * kE  + ff] = *(const float4*)&outb[(size_t)rr * kE + ff];
    }

    // ---- q-embed: gathers issue concurrently with the staging above ----
    if (t < 256) {
        const int g = t >> 5, lane = t & 31, e0 = lane * 4;
        const float f0 = (float)(e0 - 63) * (1.0f / 1024.0f);
        const float f1 = (float)(e0 - 62) * (1.0f / 1024.0f);
        const float f2 = (float)(e0 - 61) * (1.0f / 1024.0f);
        const float f3 = (float)(e0 - 60) * (1.0f / 1024.0f);
        float4 a = {0.f, 0.f, 0.f, 0.f};
        #pragma unroll
        for (int j = 0; j < 4; ++j) {
            const int s   = g * 4 + j;
            const int idx = queries[b * kS + s];          // L1-hot, 2 KB table
            const int ci  = idx < kVN ? idx : (kVN - 1);
            const float live = (idx < kVN) ? 1.0f : 0.0f;
            const float sf = (float)(s - 15);
            const float4 v = *(const float4*)&q_bias[(size_t)ci * kE + e0];
            a.x = fmaf(v.x, fmaf(f0, sf, 1.f) * live, a.x);
            a.y = fmaf(v.y, fmaf(f1, sf, 1.f) * live, a.y);
            a.z = fmaf(v.z, fmaf(f2, sf, 1.f) * live, a.z);
            a.w = fmaf(v.w, fmaf(f3, sf, 1.f) * live, a.w);
        }
        *(float4*)&part8[g][e0] = a;
    }
    __syncthreads();
    if (t < kE) {
        float s = 0.f;
        #pragma unroll
        for (int g = 0; g < 8; ++g) s += part8[g][t];
        q_s[t] = s;
    }
    __syncthreads();

    const int grp = t >> 7;
    const int e   = t & 127;

    for (int hop = 0; hop < 3; ++hop) {
        // ---- scores for own 128 rows: 8 lanes x 16 e per row ----
        {
            const int rw = t >> 3, sub = t & 7;
            const float4* qv = (const float4*)&q_s[sub * 16];
            const float4* mv = (const float4*)&mem_lds[rw * kMS + sub * 16];
            float d = 0.f;
            #pragma unroll
            for (int i = 0; i < 4; ++i) {
                const float4 m4 = mv[i], q4 = qv[i];
                d = fmaf(m4.x, q4.x, d); d = fmaf(m4.y, q4.y, d);
                d = fmaf(m4.z, q4.z, d); d = fmaf(m4.w, q4.w, d);
            }
            d += __shfl_down(d, 4);
            d += __shfl_down(d, 2);
            d += __shfl_down(d, 1);
            if (sub == 0) sc_q[rw] = __expf(d);   // no max-sub: |s| = O(1)
        }
        __syncthreads();

        // ---- numer partial ----
        {
            float acc = 0.f;
            const float* pp = &sc_q[grp * 16];
            const float* ob = &out_lds[grp * 16 * kE + e];
            #pragma unroll
            for (int j = 0; j < 16; ++j)
                acc = fmaf(pp[j], ob[j * kE], acc);
            part8[grp][e] = acc;
        }
        __syncthreads();

        const int pb = hop & 1;
        float* nq = numer + (((size_t)pb * kB + b) * 4 + qtr) * kE;
        if (t < kE) {
            float s = 0.f;
            #pragma unroll
            for (int g = 0; g < 8; ++g) s += part8[g][t];
            cstore(&nq[t], s);
        } else if (t < 192) {
            const int l = t - 128;
            float s2 = sc_q[l] + sc_q[l + 64];
            #pragma unroll
            for (int off = 32; off; off >>= 1) s2 += __shfl_down(s2, off);
            if (l == 0) cstore(&denom[((size_t)pb * kB + b) * 4 + qtr], s2);
        }

        group_barrier(ctr, 4u * (hop + 1));

        // ---- combine: xb = q + sum(numer)/sum(denom) ----
        if (t < kE) {
            const float* nn = numer + ((size_t)pb * kB + b) * 4 * kE;
            const float* dd = denom + ((size_t)pb * kB + b) * 4;
            const float ns = cload(&nn[t]) + cload(&nn[kE + t]) +
                             cload(&nn[2 * kE + t]) + cload(&nn[3 * kE + t]);
            const float ds = cload(&dd[0]) + cload(&dd[1]) +
                             cload(&dd[2]) + cload(&dd[3]);
            xb[t] = q_s[t] + ns / ds;
        }
        __syncthreads();

        // ---- q' = xb @ W (redundant, 8 k-groups of 16) ----
        {
            const float* w = (hop == 2) ? w_out : w_int;
            float acc = 0.f;
            #pragma unroll
            for (int j = 0; j < 16; ++j) {
                const int k = grp * 16 + j;
                acc = fmaf(xb[k], w[k * kE + e], acc);
            }
            part8[grp][e] = acc;
        }
        __syncthreads();
        if (t < kE) {
            float s = 0.f;
            #pragma unroll
            for (int g = 0; g < 8; ++g) s += part8[g][t];
            q_s[t] = s;
        }
        __syncthreads();
    }

    // ---- exchange relu_x: cstore -> LLC; all-64 barrier; consumers'
    //      caches never touched xg lines -> loads fill fresh from LLC ----
    if (qtr == 0 && t < kE) cstore(&xg[t * kB + b], fmaxf(q_s[t], 0.f));
    group_barrier(bar + kB, 64u);

    // ---- stage xg into LDS (8 KB): sx[e*16 + b] ----
    float* sx = mem_lds;                        // safe reuse after hops
    if (t < 512) {
        const float4 v4 = *(const float4*)&xg[t * 4];
        *(float4*)&sx[t * 4] = v4;
    }
    __syncthreads();

    // ---- fused final: out[b, v] = relu_x[b,:] . wf[:, v] ----
    // 500 v-columns per block (64 x 500 = 32000 exactly); 512 v-lanes x
    // 2 e-halves; halves combined via LDS ps[b][vt] (stride-1). The only
    // global loads in the loop are the wf stream (LLC-warm via the embed
    // prefetch); xg reads are LDS broadcasts.
    {
        const int vt = t & 511;
        const int h  = t >> 9;
        const int v  = bid * 500 + vt;
        float* ps = out_lds;                    // reuse: 16*512*4 = 32 KB
        float acc[kB];
        #pragma unroll
        for (int b2 = 0; b2 < kB; ++b2) acc[b2] = 0.f;

        if (vt < 500) {
            const int e0 = h * 64;
            #pragma unroll 8
            for (int ei = 0; ei < 64; ++ei) {
                const int ee = e0 + ei;
                const float wv = wf[(size_t)ee * kV + v];
                const float* xr = &sx[ee * kB]; // uniform addr -> broadcast
                #pragma unroll
                for (int b2 = 0; b2 < kB; ++b2)
                    acc[b2] = fmaf(xr[b2], wv, acc[b2]);
            }
            if (h == 1) {
                #pragma unroll
                for (int b2 = 0; b2 < kB; ++b2) ps[b2 * 512 + vt] = acc[b2];
            }
        }
        __syncthreads();
        if (h == 0 && vt < 500) {
            #pragma unroll
            for (int b2 = 0; b2 < kB; ++b2)
                out[(size_t)b2 * kV + v] = acc[b2] + ps[b2 * 512 + vt];
        }
    }
}

// -------------------------------------------------------------------------
extern "C" void kernel_launch(void* const* d_in, const int* in_sizes, int n_in,
                              void* d_out, int out_size, void* d_ws, size_t ws_size,
                              hipStream_t stream)
{
    const int*   queries  = (const int*)  d_in[0];
    const int*   stories  = (const int*)  d_in[1];
    const float* q_bias   = (const float*)d_in[2];
    const float* st_bias  = (const float*)d_in[3];
    const float* mem_bias = (const float*)d_in[4];
    const float* out_bias = (const float*)d_in[5];
    const float* w_int    = (const float*)d_in[6];
    const float* w_out    = (const float*)d_in[7];
    const float* w_final  = (const float*)d_in[8];
    float* out = (float*)d_out;

    // ws layout (floats): memory | output | numer | denom | xg | bar
    float* memory = (float*)d_ws;
    float* output = memory + (size_t)kB * kM * kE;        // 1,048,576
    float* numer  = output + (size_t)kB * kM * kE;        // 1,048,576
    float* denom  = numer  + 2 * kB * 4 * kE;             // 16,384
    float* xg     = denom  + 2 * kB * 4;                  // 128
    unsigned* bar = (unsigned*)(xg + kE * kB);            // 2,048

    embed_stories_kernel<<<dim3((kB * kM) / 2), dim3(256), 0, stream>>>(
        stories, st_bias, out_bias, mem_bias, w_final, memory, output, bar);

    hops_final_kernel<<<dim3(64), dim3(1024), 0, stream>>>(
        queries, q_bias, memory, output, w_int, w_out, w_final,
        numer, denom, xg, bar, out);
}